// Round 7
// baseline (1315.710 us; speedup 1.0000x reference)
//
#include <hip/hip_runtime.h>
#include <hip/hip_bf16.h>
#include <stdint.h>

#define N_T   1024
#define ROLLC 511
#define KCH   8
#define KN_LEV 48                 // knuth chain depth cap
#define RJ_LEV 24                 // rejection chain depth (T ~ 9-14)
#define CH_N  (2*KN_LEV + 4*RJ_LEV)

__device__ double   g_inp[N_T];
__device__ double   g_conv2[N_T];
__device__ double   g_area;
__device__ uint32_t g_chains[CH_N];
__device__ int      g_T;
__device__ float    g_ll5, g_aa5, g_bb5, g_inva5, g_vr5;   // rejection constants for lam=1e5

struct TF2 { uint32_t x, y; };

// Threefry-2x32, 20 rounds — matches jax._src.prng.threefry2x32 exactly.
__device__ __forceinline__ TF2 tf2x32(uint32_t k0, uint32_t k1, uint32_t c0, uint32_t c1) {
  uint32_t ks2 = k0 ^ k1 ^ 0x1BD11BDAu;
  uint32_t x0 = c0 + k0, x1 = c1 + k1;
#define TFR(r) { x0 += x1; x1 = (x1 << (r)) | (x1 >> (32 - (r))); x1 ^= x0; }
  TFR(13) TFR(15) TFR(26) TFR(6)
  x0 += k1;  x1 += ks2 + 1u;
  TFR(17) TFR(29) TFR(16) TFR(24)
  x0 += ks2; x1 += k0 + 2u;
  TFR(13) TFR(15) TFR(26) TFR(6)
  x0 += k0;  x1 += k1 + 3u;
  TFR(17) TFR(29) TFR(16) TFR(24)
  x0 += k1;  x1 += ks2 + 4u;
  TFR(13) TFR(15) TFR(26) TFR(6)
  x0 += ks2; x1 += k0 + 5u;
#undef TFR
  return {x0, x1};
}

__device__ __forceinline__ float u01_from_key(uint32_t sk0, uint32_t sk1, uint32_t m) {
  TF2 r = tf2x32(sk0, sk1, 0u, m);
  uint32_t bits = r.x ^ r.y;
  return __uint_as_float((bits >> 9) | 0x3f800000u) - 1.0f;
}

// XLA chlo.lgamma f32 decomposition (Lanczos g=7, n=9), x >= 0.5 path only.
__device__ __forceinline__ float lgamma_xla(float x) {
#pragma clang fp contract(off)
  float z = x - 1.0f;
  float sum = 1.0f;
  sum = sum + 676.5203681218851f     / (z + 1.0f);
  sum = sum + -1259.1392167224028f   / (z + 2.0f);
  sum = sum + 771.32342877765313f    / (z + 3.0f);
  sum = sum + -176.61502916214059f   / (z + 4.0f);
  sum = sum + 12.507343278686905f    / (z + 5.0f);
  sum = sum + -0.13857109526572012f  / (z + 6.0f);
  sum = sum + 9.9843695780195716e-6f / (z + 7.0f);
  sum = sum + 1.5056327351493116e-7f / (z + 8.0f);
  float t = 7.5f + z;
  float log_t = 2.0149030205422647f + log1pf(z / 7.5f);
  return 0.91893853320467274f + (z + 0.5f - t / log_t) * log_t + logf(sum);
}

__device__ __forceinline__ void rej_constants(float lam, float* ll, float* aa, float* bb,
                                              float* inva, float* vr) {
#pragma clang fp contract(off)
  *ll = logf(lam);
  float b = 0.931f + 2.53f * sqrtf(lam);
  float a = -0.059f + 0.02483f * b;
  *bb = b; *aa = a;
  *inva = 1.1239f + 1.1328f / (b - 3.4f);
  *vr = 0.9277f - 3.6224f / (b - 2.0f);
}

// Quick classification: 1 = accept, -1 = definite reject, 0 = ambiguous.
__device__ __forceinline__ int ptrs_quick(float lamr, float aa, float bb, float vr,
                                          float u, float v) {
#pragma clang fp contract(off)
  float us = 0.5f - fabsf(u);
  float kf = floorf((2.0f * aa / us + bb) * u + lamr + 0.43f);
  if ((us >= 0.07f) && (v <= vr)) return 1;
  if ((kf < 0.0f) || ((us < 0.013f) && (v > us))) return -1;
  return 0;
}

// Slow (exact) accept test for ambiguous cases.
__device__ __forceinline__ bool ptrs_slow(float lamr, float ll, float aa, float bb,
                                          float inva, float u, float v) {
#pragma clang fp contract(off)
  float us = 0.5f - fabsf(u);
  float kf = floorf((2.0f * aa / us + bb) * u + lamr + 0.43f);
  float s = logf(v * inva / (aa / (us * us) + bb));
  float t = (-lamr + kf * ll) - lgamma_xla(kf + 1.0f);
  return s <= t;
}

// One full Hormann PTRS iteration (exact).
__device__ __forceinline__ bool rej_iter(float lam, float ll, float aa, float bb,
                                         float inva, float vr, float u, float v, float* kf) {
#pragma clang fp contract(off)
  float us = 0.5f - fabsf(u);
  float k = floorf((2.0f * aa / us + bb) * u + lam + 0.43f);
  *kf = k;
  if ((us >= 0.07f) && (v <= vr)) return true;
  if ((k < 0.0f) || ((us < 0.013f) && (v > us))) return false;
  float s = logf(v * inva / (aa / (us * us) + bb));
  float t = (-lam + k * ll) - lgamma_xla(k + 1.0f);
  return s <= t;
}

// pre1: first f64 circular conv (+roll) of relu(illum) with irf -> g_inp. 8 blocks x 128.
__global__ void __launch_bounds__(128)
pre1_kernel(const float* __restrict__ illum, const float* __restrict__ irf) {
  __shared__ double xs[N_T], irfs[N_T];
  const int tid = threadIdx.x;
  for (int i = tid; i < N_T; i += 128) {
    xs[i]   = fmax((double)illum[i], 0.0);
    irfs[i] = (double)irf[i];
  }
  __syncthreads();
  const int t  = blockIdx.x * 128 + tid;
  const int tt = (t + ROLLC) & (N_T - 1);
  double acc = 0.0;
  for (int j = 0; j < N_T; ++j) acc += xs[j] * irfs[(tt - j) & (N_T - 1)];
  g_inp[t] = acc;
}

// pre2: blocks 0-7 second conv (+roll) -> g_conv2; block 8: area, chains, constants, resets.
__global__ void __launch_bounds__(128)
pre2_kernel(const float* __restrict__ irf, uint32_t* __restrict__ wcount) {
  __shared__ double inps[N_T], irfs[N_T];
  const int tid = threadIdx.x;
  if (blockIdx.x < 8) {
    for (int i = tid; i < N_T; i += 128) {
      inps[i] = g_inp[i];
      irfs[i] = (double)irf[i];
    }
    __syncthreads();
    const int t  = blockIdx.x * 128 + tid;
    const int tt = (t + ROLLC) & (N_T - 1);
    double acc = 0.0;
    for (int j = 0; j < N_T; ++j) acc += inps[j] * irfs[(tt - j) & (N_T - 1)];
    g_conv2[t] = acc;
  } else {
    if (tid == 0) {
      g_T = 1;
      wcount[0] = 0u;
      double area = 0.0;
      for (int j = 0; j < N_T; ++j) area += g_inp[j];
      g_area = area;
    } else if (tid == 1) {
      uint32_t r0 = 0u, r1 = 42u;           // knuth chain: rng,sub = split(rng)
      for (int j = 0; j < KN_LEV; ++j) {
        TF2 sub = tf2x32(r0, r1, 0u, 1u);
        TF2 nxt = tf2x32(r0, r1, 0u, 0u);
        g_chains[2*j] = sub.x; g_chains[2*j+1] = sub.y;
        r0 = nxt.x; r1 = nxt.y;
      }
    } else if (tid == 2) {
      uint32_t c0 = 0u, c1 = 42u;           // rejection chain: split(key,3)
      for (int j = 0; j < RJ_LEV; ++j) {
        TF2 nxt = tf2x32(c0, c1, 0u, 0u);
        TF2 s0  = tf2x32(c0, c1, 0u, 1u);
        TF2 s1  = tf2x32(c0, c1, 0u, 2u);
        int base = 2*KN_LEV + 4*j;
        g_chains[base]   = s0.x; g_chains[base+1] = s0.y;
        g_chains[base+2] = s1.x; g_chains[base+3] = s1.y;
        c0 = nxt.x; c1 = nxt.y;
      }
    } else if (tid == 3) {
      float ll, aa, bb, inva, vr;
      rej_constants(1e5f, &ll, &aa, &bb, &inva, &vr);
      g_ll5 = ll; g_aa5 = aa; g_bb5 = bb; g_inva5 = inva; g_vr5 = vr;
    }
  }
}

// kA: per row — lam, L1 T-eval (dense, inline slow path), group-adaptive dense
// knuth with wave-uniform trip count, einsum partial for knuth elements,
// survivor flush (ONE global atomic per block). Rejection elements left to kB.
__global__ void __launch_bounds__(256)
kA_kernel(const float* __restrict__ photon, const float* __restrict__ sbr,
          const int* __restrict__ bins, const float* __restrict__ w,
          float* __restrict__ out, uint32_t* __restrict__ wcount,
          uint2* __restrict__ recs, uint32_t cap) {
  __shared__ uint32_t ch[CH_N];
  __shared__ uint2    sstage[N_T];          // survivor staging, per-wave 256 segs
  __shared__ uint16_t tpk[N_T];             // knuth tail staging (k<<10|t)
  __shared__ float    tlp[N_T];
  __shared__ uint32_t scnts[4];
  __shared__ uint32_t sbase;
  __shared__ float    wred[4][KCH];
  const int b = blockIdx.x, tid = threadIdx.x;
  const int wv = tid >> 6, lane = tid & 63;
  for (int i = tid; i < CH_N; i += 256) ch[i] = g_chains[i];
  __syncthreads();

  const float  ph = photon[b], sb = sbr[b];
  const int    shift = bins[b] & (N_T - 1);
  const double scale = (double)ph / g_area;
  const float  r1f = ph / sb;
  const double amb = (double)r1f * (1.0 / 1024.0);
  const uint32_t mbase = (uint32_t)b << 10;
  const uint32_t ka0 = ch[2*KN_LEV+0], ka1 = ch[2*KN_LEV+1];
  const uint32_t kc0 = ch[2*KN_LEV+2], kc1 = ch[2*KN_LEV+3];
  const float ll5 = g_ll5, aa5 = g_aa5, bb5 = g_bb5, inva5 = g_inva5, vr5 = g_vr5;
  const unsigned long long lmask = (1ull << lane) - 1ull;

  uint32_t wcS = 0;   // wave-uniform survivor count
  uint32_t wcT = 0;   // wave-uniform knuth-tail count
  float acc[KCH];
#pragma unroll
  for (int k = 0; k < KCH; ++k) acc[k] = 0.0f;

  for (int i2 = 0; i2 < 4; ++i2) {
    const int t   = (wv << 8) + (i2 << 6) + lane;
    const int src = (t - shift) & (N_T - 1);
    const float lam = (float)(scale * g_conv2[src] + amb);
    const bool  isRej = (lam >= 10.0f);
    const float lamr  = isRej ? lam : 1e5f;
    const uint32_t m  = mbase + (uint32_t)t;

    // ---- L1 of the T-chain (dense, all elements)
    float u = u01_from_key(ka0, ka1, m) - 0.5f;
    float v = u01_from_key(kc0, kc1, m);
    float bbq, aaq, vrq;
    {
#pragma clang fp contract(off)
      float b2 = 0.931f + 2.53f * sqrtf(lamr);
      float aq = -0.059f + 0.02483f * b2;
      float vq = 0.9277f - 3.6224f / (b2 - 2.0f);
      bbq = isRej ? b2 : bb5;
      aaq = isRej ? aq : aa5;
      vrq = isRej ? vq : vr5;
    }
    int cls = ptrs_quick(lamr, aaq, bbq, vrq, u, v);
    bool surv;
    if (cls == 0) {   // inline slow path: once per wave-group, exact
      float ll   = isRej ? logf(lamr) : ll5;
      float inva;
      {
#pragma clang fp contract(off)
        inva = isRej ? (1.1239f + 1.1328f / (bbq - 3.4f)) : inva5;
      }
      surv = !ptrs_slow(lamr, ll, aaq, bbq, inva, u, v);
    } else {
      surv = (cls < 0);
    }
    {
      unsigned long long vote = __ballot(surv);
      uint32_t slot = wcS + (uint32_t)__popcll(vote & lmask);
      if (surv) sstage[(wv << 8) + slot] = make_uint2(m, __float_as_uint(lamr));
      wcS += (uint32_t)__popcll(vote);
    }

    // ---- knuth: group-adaptive dense depth (wave-uniform scalar loop)
    const bool kn = !isRej;
    const float neg = kn ? -lam : 1.0f;    // rej lanes: never "alive", k stays 0
    float glam = kn ? lam : 0.0f;
#pragma unroll
    for (int off = 32; off > 0; off >>= 1) glam = fmaxf(glam, __shfl_xor(glam, off, 64));
    int D = 0;
    if (glam > 0.0f) {
      D = (int)(glam + 2.0f * sqrtf(glam)) + 2;
      if (D > KN_LEV) D = KN_LEV;
    }
    float lp = 0.0f; int k = 0;
    for (int j = 0; j < D; ++j) {          // trip count wave-uniform: stays pipelined
      k += (lp > neg) ? 1 : 0;
      lp += __logf(u01_from_key(ch[2*j], ch[2*j+1], m));
    }
    const bool alive = kn && (lp > neg);   // survivors have k == D
    const float cntf = (kn && !alive) ? (float)(k - 1) : 0.0f;
#pragma unroll
    for (int kk = 0; kk < KCH; ++kk) acc[kk] += cntf * w[kk * N_T + t];
    {
      unsigned long long vote = __ballot(alive);
      uint32_t slot = wcT + (uint32_t)__popcll(vote & lmask);
      if (alive) { tpk[(wv << 8) + slot] = (uint16_t)(((uint32_t)k << 10) | (uint32_t)t);
                   tlp[(wv << 8) + slot] = lp; }
      wcT += (uint32_t)__popcll(vote);
    }
  }

  // ---- knuth tail (per-wave compacted, ~1-3% of elements)
  for (uint32_t i = lane; i < wcT; i += 64) {
    const uint32_t pk = tpk[(wv << 8) + i];
    const uint32_t t  = pk & 1023u;
    int k = (int)(pk >> 10);
    float lp = tlp[(wv << 8) + i];
    const int src = ((int)t - shift) & (N_T - 1);
    const float lam = (float)(scale * g_conv2[src] + amb);
    const float neg = -lam;
    const uint32_t m = mbase + t;
    int j = k;                              // levels consumed == k for survivors
#pragma unroll 1
    while ((lp > neg) && (j < KN_LEV)) {
      ++k;
      lp += __logf(u01_from_key(ch[2*j], ch[2*j+1], m));
      ++j;
    }
    const float cntf = (float)(k - 1);
#pragma unroll
    for (int kk = 0; kk < KCH; ++kk) acc[kk] += cntf * w[kk * N_T + t];
  }

  // ---- block einsum reduce + survivor flush
#pragma unroll
  for (int kk = 0; kk < KCH; ++kk) {
    float vv = acc[kk];
    for (int off = 32; off > 0; off >>= 1) vv += __shfl_down(vv, off, 64);
    if (lane == 0) wred[wv][kk] = vv;
  }
  if (lane == 0) scnts[wv] = wcS;
  __syncthreads();
  if (tid == 0) sbase = atomicAdd(wcount, scnts[0] + scnts[1] + scnts[2] + scnts[3]);
  if (tid < KCH)
    out[b * KCH + tid] = wred[0][tid] + wred[1][tid] + wred[2][tid] + wred[3][tid];
  __syncthreads();
  uint32_t pre = 0;
  for (int ww = 0; ww < wv; ++ww) pre += scnts[ww];
  const uint32_t base = sbase + pre;
  for (uint32_t i = lane; i < wcS; i += 64) {
    const uint32_t g = base + i;
    const uint2 r = sstage[(wv << 8) + i];
    if (g < cap) {
      recs[g] = r;
    } else {  // ws overflow (not expected): resolve exactly inline
      const uint32_t m = r.x; const float lamr = __uint_as_float(r.y);
      float ll, aaf, bbf, invaf, vrf;
      if (lamr == 1e5f) { ll = ll5; aaf = aa5; bbf = bb5; invaf = inva5; vrf = vr5; }
      else rej_constants(lamr, &ll, &aaf, &bbf, &invaf, &vrf);
      int jf = RJ_LEV;
#pragma unroll 1
      for (int j = 1; j < RJ_LEV; ++j) {
        float uu = u01_from_key(ch[2*KN_LEV + 4*j], ch[2*KN_LEV + 4*j + 1], m) - 0.5f;
        float vv = u01_from_key(ch[2*KN_LEV + 4*j + 2], ch[2*KN_LEV + 4*j + 3], m);
        float kk;
        if (rej_iter(lamr, ll, aaf, bbf, invaf, vrf, uu, vv, &kk)) { jf = j + 1; break; }
      }
      atomicMax(&g_T, jf);
    }
  }
}

// t2: levels 2+ for compacted survivors only; global T via atomicMax.
__global__ void __launch_bounds__(256)
t2_kernel(const uint32_t* __restrict__ wcount, const uint2* __restrict__ recs, uint32_t cap) {
  __shared__ uint32_t chs[4*RJ_LEV];
  __shared__ int bmax;
  const int tid = threadIdx.x;
  if (tid < 4*RJ_LEV) chs[tid] = g_chains[2*KN_LEV + tid];
  if (tid == 0) bmax = 1;
  __syncthreads();
  uint32_t n = *wcount; if (n > cap) n = cap;
  const float ll5 = g_ll5, aa5 = g_aa5, bb5 = g_bb5, inva5 = g_inva5, vr5 = g_vr5;
  int mymax = 1;
  for (uint32_t gi = blockIdx.x * 256u + tid; gi < n; gi += gridDim.x * 256u) {
    uint2 r = recs[gi];
    const uint32_t m = r.x; const float lamr = __uint_as_float(r.y);
    float ll, aa, bbv, inva, vr;
    if (lamr == 1e5f) { ll = ll5; aa = aa5; bbv = bb5; inva = inva5; vr = vr5; }
    else rej_constants(lamr, &ll, &aa, &bbv, &inva, &vr);
    int jf = RJ_LEV;
#pragma unroll 1
    for (int j = 1; j < RJ_LEV; ++j) {
      float uu = u01_from_key(chs[4*j], chs[4*j+1], m) - 0.5f;
      float vv = u01_from_key(chs[4*j+2], chs[4*j+3], m);
      float kk;
      if (rej_iter(lamr, ll, aa, bbv, inva, vr, uu, vv, &kk)) { jf = j + 1; break; }
    }
    mymax = max(mymax, jf);
  }
  for (int off = 32; off > 0; off >>= 1) mymax = max(mymax, __shfl_down(mymax, off, 64));
  if ((tid & 63) == 0) atomicMax(&bmax, mymax);
  __syncthreads();
  if (tid == 0) atomicMax(&g_T, bmax);
}

// kB: re-walk rows; lam>=10 lanes do backward-from-T rejection with dense-4 trips;
// block-accumulated einsum contribution added to out via 8 non-contending atomics.
__global__ void __launch_bounds__(256)
kB_kernel(const float* __restrict__ photon, const float* __restrict__ sbr,
          const int* __restrict__ bins, const float* __restrict__ w,
          float* __restrict__ out) {
  __shared__ int haveRej;
  __shared__ float wred[4][KCH];
  const int b = blockIdx.x, tid = threadIdx.x;
  const int wv = tid >> 6, lane = tid & 63;
  if (tid == 0) haveRej = 0;
  __syncthreads();
  const float  ph = photon[b], sb = sbr[b];
  const int    shift = bins[b] & (N_T - 1);
  const double scale = (double)ph / g_area;
  const float  r1f = ph / sb;
  const double amb = (double)r1f * (1.0 / 1024.0);
  const uint32_t mbase = (uint32_t)b << 10;
  const int T = g_T;

  float acc[KCH];
#pragma unroll
  for (int k = 0; k < KCH; ++k) acc[k] = 0.0f;
  bool any = false;

  for (int i2 = 0; i2 < 4; ++i2) {
    const int t   = (wv << 8) + (i2 << 6) + lane;
    const int src = (t - shift) & (N_T - 1);
    const float lam = (float)(scale * g_conv2[src] + amb);
    if (lam >= 10.0f) {
      any = true;
      const uint32_t m = mbase + (uint32_t)t;
      float ll, aa, bbv, inva, vr;
      rej_constants(lam, &ll, &aa, &bbv, &inva, &vr);
      float kout = -1.0f;
      bool found = false;
#pragma unroll 1
      for (int jj = T - 1; jj >= 0 && !found; jj -= 4) {
        float kf0, kf1, kf2, kf3;
        bool a0 = false, a1 = false, a2 = false, a3 = false;
        {
          const uint32_t* c = g_chains + 2*KN_LEV + 4*jj;
          a0 = rej_iter(lam, ll, aa, bbv, inva, vr,
                        u01_from_key(c[0], c[1], m) - 0.5f,
                        u01_from_key(c[2], c[3], m), &kf0);
        }
        if (jj - 1 >= 0) {
          const uint32_t* c = g_chains + 2*KN_LEV + 4*(jj-1);
          a1 = rej_iter(lam, ll, aa, bbv, inva, vr,
                        u01_from_key(c[0], c[1], m) - 0.5f,
                        u01_from_key(c[2], c[3], m), &kf1);
        }
        if (jj - 2 >= 0) {
          const uint32_t* c = g_chains + 2*KN_LEV + 4*(jj-2);
          a2 = rej_iter(lam, ll, aa, bbv, inva, vr,
                        u01_from_key(c[0], c[1], m) - 0.5f,
                        u01_from_key(c[2], c[3], m), &kf2);
        }
        if (jj - 3 >= 0) {
          const uint32_t* c = g_chains + 2*KN_LEV + 4*(jj-3);
          a3 = rej_iter(lam, ll, aa, bbv, inva, vr,
                        u01_from_key(c[0], c[1], m) - 0.5f,
                        u01_from_key(c[2], c[3], m), &kf3);
        }
        if      (a0) { kout = kf0; found = true; }
        else if (a1) { kout = kf1; found = true; }
        else if (a2) { kout = kf2; found = true; }
        else if (a3) { kout = kf3; found = true; }
      }
#pragma unroll
      for (int kk = 0; kk < KCH; ++kk) acc[kk] += kout * w[kk * N_T + t];
    }
  }

  if (any) haveRej = 1;          // benign race: all writers store 1
  __syncthreads();
  if (!haveRej) return;
#pragma unroll
  for (int kk = 0; kk < KCH; ++kk) {
    float vv = acc[kk];
    for (int off = 32; off > 0; off >>= 1) vv += __shfl_down(vv, off, 64);
    if (lane == 0) wred[wv][kk] = vv;
  }
  __syncthreads();
  if (tid < KCH)
    atomicAdd(&out[b * KCH + tid], wred[0][tid] + wred[1][tid] + wred[2][tid] + wred[3][tid]);
}

extern "C" void kernel_launch(void* const* d_in, const int* in_sizes, int n_in,
                              void* d_out, int out_size, void* d_ws, size_t ws_size,
                              hipStream_t stream) {
  (void)n_in; (void)out_size;
  const float* illum  = (const float*)d_in[0];
  const float* photon = (const float*)d_in[1];
  const float* sbr    = (const float*)d_in[2];
  const float* irf    = (const float*)d_in[3];
  const float* w      = (const float*)d_in[4];
  const int*   bins   = (const int*)d_in[5];
  float* out = (float*)d_out;
  const int B = in_sizes[1];

  uint32_t* wcount = (uint32_t*)d_ws;
  uint2*    recs   = (uint2*)((char*)d_ws + 16);
  uint32_t  cap    = (ws_size > 16) ? (uint32_t)((ws_size - 16) / sizeof(uint2)) : 0u;

  pre1_kernel<<<8, 128, 0, stream>>>(illum, irf);
  pre2_kernel<<<9, 128, 0, stream>>>(irf, wcount);
  kA_kernel<<<B, 256, 0, stream>>>(photon, sbr, bins, w, out, wcount, recs, cap);
  t2_kernel<<<2048, 256, 0, stream>>>(wcount, recs, cap);
  kB_kernel<<<B, 256, 0, stream>>>(photon, sbr, bins, w, out);
}